// Round 10
// baseline (496.339 us; speedup 1.0000x reference)
//
#include <hip/hip_runtime.h>
#include <hip/hip_cooperative_groups.h>
#include <math.h>

namespace cg = cooperative_groups;

#define N_NODES 50000
#define N_EDGES 500000
#define DIM     128
#define NGRAPH  50
#define NPGC    1000
#define KSEL    500
#define SORT_N  1024
#define NBE     489    // ceil(N_EDGES / 1024)
#define NBN     49     // ceil(N_NODES / 1024)

// phase chunk counts
#define WPREP_C 64
#define RANK_C  1954   // ceil(N_EDGES/256)
#define DOTS_C  12500  // N_NODES/4
#define P0_TOT  (WPREP_C + RANK_C + DOTS_C)
#define GEMM_C  782    // ceil(N_NODES/64)
#define P1_TOT  (GEMM_C + NBN + 196)
#define P2_TOT  1954
#define GATH_C  6250
#define P4_TOT  (NBE + GATH_C)
#define P5_TOT  1954

typedef short s16x8 __attribute__((ext_vector_type(8)));  // 8 bf16 (4 VGPRs)
typedef float f32x4 __attribute__((ext_vector_type(4)));  // MFMA acc

// float -> bf16(hi) + bf16(lo of residual), round-to-nearest-even
__device__ __forceinline__ void f2bf2(float v, unsigned short& h, unsigned short& l) {
    unsigned u = __float_as_uint(v);
    unsigned hb = (u + 0x7FFFu + ((u >> 16) & 1u)) >> 16;
    h = (unsigned short)hb;
    float r = v - __uint_as_float(hb << 16);
    unsigned u2 = __float_as_uint(r);
    l = (unsigned short)((u2 + 0x7FFFu + ((u2 >> 16) & 1u)) >> 16);
}

// ====================== cooperative mega-kernel ======================
// P0: wprep || rank-atomics (cursor->deg, rank[e]) || dots (f64 ranking dots)
// P1: MFMA gemm (bf16x3 split) || rowoff scan || dinv
// P2: CSR pure scatter (rowoff + rank, no atomics)
// P3: per-graph f64 score gather + tanh + bitonic top-k
// P4: edge flag+scan || fusion gather (x_out, x_ae)
// P5: edge compaction scatter
// LDS 48KB union; bsN persists at +12288 from P2 through P4.

__global__ __launch_bounds__(256) void mega(
    const float* __restrict__ x, const int* __restrict__ src, const int* __restrict__ dst,
    const float* __restrict__ Ws, const float* __restrict__ bs,
    const float* __restrict__ Wf, const float* __restrict__ bf,
    const float* __restrict__ Wfu, const float* __restrict__ bfu,
    int* cursor, int* nodemap, int* rank,
    double* pack, double* sf, float* dinvf, float* scoref_sel,
    int* perm, int* rowoff, int* epos, int* bsumsE, int* bsumsN,
    int* csr, float* xw, unsigned short* Wth, unsigned short* Wtl,
    float* out, long M, long o2, long o3, long o4)
{
    cg::grid_group grid = cg::this_grid();
    __shared__ __align__(16) unsigned char smem[49152];
    const int t = threadIdx.x;
    const int lane = t & 63, wid = t >> 6;
    const int G = gridDim.x;

    // ---------------- Phase 0 ----------------
    for (int c = blockIdx.x; c < P0_TOT; c += G) {
        if (c < WPREP_C) {
            int wi = c * 256 + t;                    // 16384 elems
            int k = wi >> 7, ch = wi & 127;
            unsigned short h, l;
            f2bf2(Wfu[wi], h, l);
            int hh = k >> 6, kl = k & 63;
            int pos = hh * 8192 + ch * 64 + ((((kl >> 3) ^ (ch & 7))) << 3) + (kl & 7);
            Wth[pos] = h; Wtl[pos] = l;
        } else if (c < WPREP_C + RANK_C) {
            int e = (c - WPREP_C) * 256 + t;
            if (e < N_EDGES) rank[e] = atomicAdd(&cursor[dst[e]], 1);
        } else {
            int node = (c - WPREP_C - RANK_C) * 4 + wid;   // exactly 50000
            const float* xr = x + (size_t)node * DIM;
            double x1 = (double)xr[lane], x2 = (double)xr[lane + 64];
            double ps = x1 * (double)Ws[lane] + x2 * (double)Ws[lane + 64];
            double pf = x1 * (double)Wf[lane] + x2 * (double)Wf[lane + 64];
            for (int off = 32; off > 0; off >>= 1) {
                ps += __shfl_down(ps, off, 64);
                pf += __shfl_down(pf, off, 64);
            }
            if (lane == 0) { pack[2 * node + 1] = ps; sf[node] = pf + (double)bf[0]; }
        }
    }
    grid.sync();

    // ---------------- Phase 1 ----------------
    for (int c = blockIdx.x; c < P1_TOT; c += G) {
        if (c < GEMM_C) {
            unsigned short* XH = (unsigned short*)smem;
            unsigned short* XL = XH + 4096;
            unsigned short* WH = XH + 8192;
            unsigned short* WL = XH + 16384;
            const int q = lane >> 4, mm = lane & 15;
            int node_base = c * 64;
            f32x4 acc[8];
            #pragma unroll
            for (int ct = 0; ct < 8; ct++) acc[ct] = (f32x4){0.f, 0.f, 0.f, 0.f};
            for (int h = 0; h < 2; h++) {
                {   // W^T halves: linear b128 copies (pre-swizzled in P0)
                    const s16x8* GH = (const s16x8*)(Wth + h * 8192);
                    const s16x8* GL = (const s16x8*)(Wtl + h * 8192);
                    s16x8* LH = (s16x8*)WH;
                    s16x8* LL = (s16x8*)WL;
                    #pragma unroll
                    for (int i = 0; i < 4; i++) {
                        LH[t + i * 256] = GH[t + i * 256];
                        LL[t + i * 256] = GL[t + i * 256];
                    }
                }
                #pragma unroll
                for (int i = 0; i < 4; i++) {        // x half -> bf16 hi/lo swizzled
                    int f = t + i * 256;
                    int r = f >> 4, c4 = f & 15;
                    int node = node_base + r;
                    float4 v = make_float4(0.f, 0.f, 0.f, 0.f);
                    if (node < N_NODES) v = *(const float4*)&x[(size_t)node * DIM + h * 64 + c4 * 4];
                    unsigned short h0, l0, h1, l1, h2, l2, h3, l3;
                    f2bf2(v.x, h0, l0); f2bf2(v.y, h1, l1);
                    f2bf2(v.z, h2, l2); f2bf2(v.w, h3, l3);
                    int off = r * 64 + ((((c4 >> 1) ^ (r & 7))) << 3) + ((c4 & 1) << 2);
                    *(uint2*)&XH[off] = make_uint2((unsigned)h0 | ((unsigned)h1 << 16),
                                                   (unsigned)h2 | ((unsigned)h3 << 16));
                    *(uint2*)&XL[off] = make_uint2((unsigned)l0 | ((unsigned)l1 << 16),
                                                   (unsigned)l2 | ((unsigned)l3 << 16));
                }
                __syncthreads();
                #pragma unroll
                for (int kk2 = 0; kk2 < 2; kk2++) {  // two K=32 chunks per half
                    int jb = kk2 * 4 + q;
                    int aoff = (wid * 16 + mm) * 64 + ((jb ^ (mm & 7)) << 3);
                    s16x8 ah = *(const s16x8*)&XH[aoff];
                    s16x8 al = *(const s16x8*)&XL[aoff];
                    #pragma unroll
                    for (int ct = 0; ct < 8; ct++) {
                        int ch = ct * 16 + mm;
                        int boff = ch * 64 + ((jb ^ (ch & 7)) << 3);
                        s16x8 bh = *(const s16x8*)&WH[boff];
                        s16x8 bl = *(const s16x8*)&WL[boff];
                        acc[ct] = __builtin_amdgcn_mfma_f32_16x16x32_bf16(ah, bh, acc[ct], 0, 0, 0);
                        acc[ct] = __builtin_amdgcn_mfma_f32_16x16x32_bf16(ah, bl, acc[ct], 0, 0, 0);
                        acc[ct] = __builtin_amdgcn_mfma_f32_16x16x32_bf16(al, bh, acc[ct], 0, 0, 0);
                    }
                }
                __syncthreads();
            }
            #pragma unroll
            for (int ct = 0; ct < 8; ct++) {
                #pragma unroll
                for (int r = 0; r < 4; r++) {
                    int node = node_base + wid * 16 + q * 4 + r;
                    if (node < N_NODES) xw[(size_t)node * DIM + ct * 16 + mm] = acc[ct][r];
                }
            }
        } else if (c < GEMM_C + NBN) {
            int* ws4 = (int*)(smem + 12544);
            int chunk = c - GEMM_C;
            int base = chunk * 1024 + t * 4;
            int v0 = (base + 0 < N_NODES) ? cursor[base + 0] : 0;
            int v1 = (base + 1 < N_NODES) ? cursor[base + 1] : 0;
            int v2 = (base + 2 < N_NODES) ? cursor[base + 2] : 0;
            int v3 = (base + 3 < N_NODES) ? cursor[base + 3] : 0;
            int s4 = v0 + v1 + v2 + v3;
            int incl = s4;
            #pragma unroll
            for (int off = 1; off < 64; off <<= 1) {
                int u = __shfl_up(incl, off, 64);
                if (lane >= off) incl += u;
            }
            if (lane == 63) ws4[wid] = incl;
            __syncthreads();
            int woff = 0;
            #pragma unroll
            for (int w = 0; w < 4; w++) if (w < wid) woff += ws4[w];
            int excl = incl - s4 + woff;
            if (base + 0 < N_NODES) rowoff[base + 0] = excl;
            if (base + 1 < N_NODES) rowoff[base + 1] = excl + v0;
            if (base + 2 < N_NODES) rowoff[base + 2] = excl + v0 + v1;
            if (base + 3 < N_NODES) rowoff[base + 3] = excl + v0 + v1 + v2;
            if (t == 255) bsumsN[chunk] = woff + incl;
            __syncthreads();                         // protect ws4 for next chunk
        } else {
            int i = (c - GEMM_C - NBN) * 256 + t;
            if (i < N_NODES) {
                double di = 1.0 / sqrt((double)(cursor[i] + 1));
                pack[2 * i] = di;
                dinvf[i] = (float)di;
            }
        }
    }
    grid.sync();

    // ---------------- Phase 2: CSR pure scatter ----------------
    {
        int* bsN = (int*)(smem + 12288);
        if (t < 64) {
            int v = (t < NBN) ? bsumsN[t] : 0;
            int incl = v;
            #pragma unroll
            for (int off = 1; off < 64; off <<= 1) {
                int u = __shfl_up(incl, off, 64);
                if (t >= off) incl += u;
            }
            bsN[t] = incl - v;
        }
        __syncthreads();
        for (int c = blockIdx.x; c < P2_TOT; c += G) {
            int e = c * 256 + t;
            if (e < N_EDGES) {
                int d = dst[e];
                csr[rowoff[d] + bsN[d >> 10] + rank[e]] = src[e];
            }
        }
    }
    grid.sync();

    // ---------------- Phase 3: score + top-k (bsN persists at +12288) ----------------
    {
        double* key = (double*)smem;                 // 8KB
        int* idx = (int*)(smem + 8192);              // 4KB
        int* bsN = (int*)(smem + 12288);
        const double A = 0.6, OMA = 1.0 - 0.6;
        double bsv = (double)bs[0];
        for (int g = blockIdx.x; g < NGRAPH; g += G) {
            for (int i = t; i < SORT_N; i += 256) {
                if (i < NPGC) {
                    int node = g * NPGC + i;
                    int base = rowoff[node] + bsN[node >> 10];
                    int cnt  = cursor[node];
                    double acc0 = 0.0, acc1 = 0.0;
                    int e = 0;
                    for (; e + 2 <= cnt; e += 2) {
                        int s0 = csr[base + e];
                        int s1 = csr[base + e + 1];
                        double2 p0 = ((const double2*)pack)[s0];
                        double2 p1 = ((const double2*)pack)[s1];
                        acc0 += p0.x * p0.y;
                        acc1 += p1.x * p1.y;
                    }
                    if (e < cnt) {
                        int s0 = csr[base + e];
                        double2 p0 = ((const double2*)pack)[s0];
                        acc0 += p0.x * p0.y;
                    }
                    double2 pn = ((const double2*)pack)[node];
                    double tot = pn.x * (acc0 + acc1) + pn.x * pn.x * pn.y + bsv;
                    key[i] = tanh(A * tot + OMA * sf[node]);
                    idx[i] = i;
                } else { key[i] = -1e300; idx[i] = i; }
            }
            __syncthreads();
            for (int size = 2; size <= SORT_N; size <<= 1) {
                for (int stride = size >> 1; stride > 0; stride >>= 1) {
                    #pragma unroll
                    for (int jj = 0; jj < 2; jj++) {
                        int j = t + jj * 256;
                        int a = ((j & ~(stride - 1)) << 1) | (j & (stride - 1));
                        int b = a | stride;
                        bool descFirst = ((a & size) == 0);
                        double ka = key[a], kb = key[b];
                        int ia = idx[a], ib = idx[b];
                        bool aAfterB = (ka < kb) || (ka == kb && ia > ib);  // stable descending
                        if (descFirst ? aAfterB : !aAfterB) {
                            key[a] = kb; key[b] = ka;
                            idx[a] = ib; idx[b] = ia;
                        }
                    }
                    __syncthreads();
                }
            }
            for (int j = t; j < KSEL; j += 256) {
                int node = g * NPGC + idx[j];
                int pos  = g * KSEL + j;
                perm[pos]       = node;
                nodemap[node]   = pos + 1;           // 0 = unselected
                scoref_sel[pos] = (float)key[j];
                out[o2 + pos]   = (float)g;          // batch_out
                out[o3 + pos]   = (float)node;       // perm
            }
            __syncthreads();                         // before next g rewrites key
        }
    }
    grid.sync();

    // ---------------- Phase 4: edge flag+scan || fusion gather ----------------
    {
        int* bsN = (int*)(smem + 12288);
        int* ws4 = (int*)(smem + 12544);
        for (int c = blockIdx.x; c < P4_TOT; c += G) {
            if (c < NBE) {
                int base = c * 1024 + t * 4;
                int v0 = 0, v1 = 0, v2 = 0, v3 = 0;
                if (base + 0 < N_EDGES) v0 = (nodemap[src[base + 0]] > 0 && nodemap[dst[base + 0]] > 0);
                if (base + 1 < N_EDGES) v1 = (nodemap[src[base + 1]] > 0 && nodemap[dst[base + 1]] > 0);
                if (base + 2 < N_EDGES) v2 = (nodemap[src[base + 2]] > 0 && nodemap[dst[base + 2]] > 0);
                if (base + 3 < N_EDGES) v3 = (nodemap[src[base + 3]] > 0 && nodemap[dst[base + 3]] > 0);
                int s4 = v0 + v1 + v2 + v3;
                int incl = s4;
                #pragma unroll
                for (int off = 1; off < 64; off <<= 1) {
                    int u = __shfl_up(incl, off, 64);
                    if (lane >= off) incl += u;
                }
                if (lane == 63) ws4[wid] = incl;
                __syncthreads();
                int woff = 0;
                #pragma unroll
                for (int w = 0; w < 4; w++) if (w < wid) woff += ws4[w];
                int excl = incl - s4 + woff;
                if (base + 0 < N_EDGES) epos[base + 0] = excl;
                if (base + 1 < N_EDGES) epos[base + 1] = excl + v0;
                if (base + 2 < N_EDGES) epos[base + 2] = excl + v0 + v1;
                if (base + 3 < N_EDGES) epos[base + 3] = excl + v0 + v1 + v2;
                if (t == 255) bsumsE[c] = woff + incl;
                __syncthreads();                     // protect ws4 for next chunk
            } else {
                int wave = (c - NBE) * 4 + wid;      // exactly 25000
                int p = perm[wave];
                float dpf = dinvf[p];
                int c2 = lane * 2;
                float2 v = ((const float2*)(xw + (size_t)p * DIM))[lane];
                float nself = dpf * dpf;
                float ax = nself * v.x, ay = nself * v.y;
                int beg = rowoff[p] + bsN[p >> 10], cnt = cursor[p];
                int i = 0;
                for (; i + 2 <= cnt; i += 2) {
                    int s0 = csr[beg + i];
                    int s1 = csr[beg + i + 1];
                    float2 u0 = ((const float2*)(xw + (size_t)s0 * DIM))[lane];
                    float2 u1 = ((const float2*)(xw + (size_t)s1 * DIM))[lane];
                    float n0 = dinvf[s0] * dpf, n1 = dinvf[s1] * dpf;
                    ax += n0 * u0.x; ay += n0 * u0.y;
                    ax += n1 * u1.x; ay += n1 * u1.y;
                }
                if (i < cnt) {
                    int s0 = csr[beg + i];
                    float2 u0 = ((const float2*)(xw + (size_t)s0 * DIM))[lane];
                    float n0 = dinvf[s0] * dpf;
                    ax += n0 * u0.x; ay += n0 * u0.y;
                }
                ax += bfu[c2];
                ay += bfu[c2 + 1];
                float sc = scoref_sel[wave];
                size_t ro = (size_t)wave * DIM + c2;
                out[o4 + ro]     = ax;               // x_ae
                out[o4 + ro + 1] = ay;
                out[ro]          = ax * sc;          // x_out
                out[ro + 1]      = ay * sc;
            }
        }
    }
    grid.sync();

    // ---------------- Phase 5: edge compaction ----------------
    {
        int* bsE = (int*)smem;                       // 512 ints
        if (t < 64) {
            int carry = 0;
            #pragma unroll
            for (int cc = 0; cc < 8; cc++) {
                int i = cc * 64 + t;
                int v = (i < NBE) ? bsumsE[i] : 0;
                int incl = v;
                #pragma unroll
                for (int off = 1; off < 64; off <<= 1) {
                    int u = __shfl_up(incl, off, 64);
                    if (t >= off) incl += u;
                }
                if (i < 512) bsE[i] = incl - v + carry;
                carry += __shfl(incl, 63, 64);
            }
        }
        __syncthreads();
        const long o1 = 3200000L;
        for (int c = blockIdx.x; c < P5_TOT; c += G) {
            int e = c * 256 + t;
            if (e < N_EDGES) {
                int r = nodemap[src[e]], cc = nodemap[dst[e]];
                if (r > 0 && cc > 0) {
                    int pos = epos[e] + bsE[e >> 10];
                    out[o1 + pos]     = (float)(r - 1);
                    out[o1 + M + pos] = (float)(cc - 1);
                }
            }
        }
    }
}

// ---------------- host ----------------

extern "C" void kernel_launch(void* const* d_in, const int* in_sizes, int n_in,
                              void* d_out, int out_size, void* d_ws, size_t ws_size,
                              hipStream_t stream) {
    const float* x    = (const float*)d_in[0];
    const int*   ei   = (const int*)d_in[1];
    const int*   src  = ei;
    const int*   dst  = ei + N_EDGES;
    const float* W_s  = (const float*)d_in[3];
    const float* b_s  = (const float*)d_in[4];
    const float* W_f  = (const float*)d_in[5];
    const float* b_f  = (const float*)d_in[6];
    const float* W_fu = (const float*)d_in[7];
    const float* b_fu = (const float*)d_in[8];
    float* out = (float*)d_out;

    char* wsp = (char*)d_ws;
    size_t off = 0;
    auto take = [&](size_t bytes) -> char* {
        char* p = wsp + off;
        off = (off + bytes + 255) & ~(size_t)255;
        return p;
    };
    // zero-cluster (single memset): cursor (becomes deg) | nodemap (0 = unselected)
    char*   zbase      = wsp;
    int*    cursor     = (int*)   take((size_t)N_NODES * 4);
    int*    nodemap    = (int*)   take((size_t)N_NODES * 4);
    size_t  zbytes     = off;
    int*    rank       = (int*)   take((size_t)N_EDGES * 4);
    double* pack       = (double*)take((size_t)N_NODES * 16);  // {dinv, xw_s} per node
    double* sf         = (double*)take((size_t)N_NODES * 8);
    float*  dinvf      = (float*) take((size_t)N_NODES * 4);
    float*  scoref_sel = (float*) take((size_t)NGRAPH * KSEL * 4);
    int*    perm       = (int*)   take((size_t)NGRAPH * KSEL * 4);
    int*    rowoff     = (int*)   take((size_t)N_NODES * 4);
    int*    epos       = (int*)   take((size_t)N_EDGES * 4);
    int*    bsumsE     = (int*)   take((size_t)1024 * 4);
    int*    bsumsN     = (int*)   take((size_t)1024 * 4);
    int*    csr        = (int*)   take((size_t)N_EDGES * 4);
    float*  xw         = (float*) take((size_t)N_NODES * DIM * 4);
    unsigned short* Wth = (unsigned short*)take((size_t)16384 * 2);
    unsigned short* Wtl = (unsigned short*)take((size_t)16384 * 2);

    // output layout: x_out[25000*128] | edge_index_new[2*M] | batch_out | perm | x_ae[25000*128]
    long M  = ((long)out_size - 6450000L) / 2;
    long o1 = 3200000L;
    long o2 = o1 + 2 * M;
    long o3 = o2 + (long)NGRAPH * KSEL;
    long o4 = o3 + (long)NGRAPH * KSEL;

    hipMemsetAsync(zbase, 0, zbytes, stream);

    // occupancy-clamped cooperative grid (48KB LDS -> expect 3 blocks/CU -> 768)
    int maxb = 0;
    if (hipOccupancyMaxActiveBlocksPerMultiprocessor(&maxb, (const void*)mega, 256, 0)
        != hipSuccess || maxb <= 0) maxb = 1;
    if (maxb > 3) maxb = 3;
    int G = maxb * 256;

    void* args[] = {
        (void*)&x, (void*)&src, (void*)&dst,
        (void*)&W_s, (void*)&b_s, (void*)&W_f, (void*)&b_f, (void*)&W_fu, (void*)&b_fu,
        (void*)&cursor, (void*)&nodemap, (void*)&rank,
        (void*)&pack, (void*)&sf, (void*)&dinvf, (void*)&scoref_sel,
        (void*)&perm, (void*)&rowoff, (void*)&epos, (void*)&bsumsE, (void*)&bsumsN,
        (void*)&csr, (void*)&xw, (void*)&Wth, (void*)&Wtl,
        (void*)&out, (void*)&M, (void*)&o2, (void*)&o3, (void*)&o4
    };
    hipLaunchCooperativeKernel((const void*)mega, dim3(G), dim3(256), args, 0, stream);
}